// Round 4
// baseline (81.713 us; speedup 1.0000x reference)
//
#include <hip/hip_runtime.h>

// KAN 2x2 convolution, stride 1, summed over C=16 channels.
// x: (8,16,128,128) fp32 -> out: (8,1,127,127) fp32
//
// Round-4 structure (single dispatch, no atomics, no memset):
//  - uniform-knot cubic B-spline folded into per-(interval t, position p)
//    cubic coefficient table coef[11][4] (float4, 704 B LDS) — exact
//    reformulation of Cox-de-Boor for the uniform grid (rounds 1-3).
//  - block = 256 threads owns a 32x8 output tile and loops ALL 16 channels:
//    phase A evaluates each of the 33x9 input values ONCE (silu + interval +
//    4 Horner cubics) into SoA LDS; phase B gathers the 4 window neighbors.
//  - 512 blocks (2 blocks/CU, 16 waves/CU). Each output element is written
//    by exactly one thread with a plain store -> no pre-zero, no atomics.

#define IN_F 4
#define N_COEF 8
#define N_INT 11   // knot intervals
#define TW 32      // output tile width
#define TH 8       // output tile height
#define LW 33      // input tile width  (TW+1)
#define LH 9       // input tile height (TH+1)
#define NV (LW * LH)  // 297 input values per tile

__device__ __forceinline__ float silu(float x) {
    return x * __builtin_amdgcn_rcpf(1.0f + __expf(-x));
}

__global__ __launch_bounds__(256) void kan_conv_kernel(
    const float* __restrict__ x,
    const float* __restrict__ base_w,    // (1,4)
    const float* __restrict__ spline_w,  // (1,4,8)
    const float* __restrict__ spline_s,  // (1,4)
    const float* __restrict__ grid,      // (4,12) identical uniform rows
    float* __restrict__ out,
    int B, int C, int H, int W)
{
    const int Ho = H - 1, Wo = W - 1;  // 127,127

    __shared__ float4 coef[N_INT][IN_F];   // [t][p] -> cubic coeffs (c0..c3)
    __shared__ float  sfeat[IN_F][NV];     // per-position features, SoA
    __shared__ float  s_misc[6];           // bw0..bw3, g0, invh

    const int tid = threadIdx.x;

    // ---- one-time table build (tid 0..43) ----
    if (tid < N_INT * IN_F) {
        const int t = tid / IN_F;
        const int p = tid % IN_F;
        // uniform cubic B-spline blending matrix (power basis in u)
        const float M[4][4] = {
            {1.f/6.f, -3.f/6.f,  3.f/6.f, -1.f/6.f},
            {4.f/6.f,  0.f,     -6.f/6.f,  3.f/6.f},
            {1.f/6.f,  3.f/6.f,  3.f/6.f, -3.f/6.f},
            {0.f,      0.f,      0.f,      1.f/6.f}};
        const float scal = spline_s[p];
        float c0 = 0.f, c1 = 0.f, c2 = 0.f, c3 = 0.f;
        #pragma unroll
        for (int m = 0; m < 4; ++m) {
            const int j = t - 3 + m;
            const float w = (j >= 0 && j < N_COEF)
                              ? spline_w[p * N_COEF + j] * scal : 0.f;
            c0 += M[m][0] * w; c1 += M[m][1] * w;
            c2 += M[m][2] * w; c3 += M[m][3] * w;
        }
        coef[t][p] = make_float4(c0, c1, c2, c3);
    }
    if (tid < IN_F) s_misc[tid] = base_w[tid];
    if (tid == 4)   s_misc[4] = grid[0];
    if (tid == 5)   s_misc[5] = 1.0f / (grid[1] - grid[0]);

    // ---- block decomposition: 4 xtiles x 16 ytiles x 8 batches = 512 ----
    int bid = blockIdx.x;
    const int txi = bid & 3;  bid >>= 2;
    const int tyi = bid & 15; bid >>= 4;
    const int b   = bid;
    const int tx0 = txi * TW, ty0 = tyi * TH;

    const int lx = tid & (TW - 1);
    const int ly = tid >> 5;           // 0..7
    const int oy = ty0 + ly, ox = tx0 + lx;

    __syncthreads();
    const float bw[4] = {s_misc[0], s_misc[1], s_misc[2], s_misc[3]};
    const float g0 = s_misc[4], invh = s_misc[5];

    float acc = 0.f;
    const float* __restrict__ xb = x + ((size_t)b * C * H) * W;

    for (int c = 0; c < 16; ++c) {
        const float* __restrict__ xc = xb + (size_t)c * H * W;

        if (c > 0) __syncthreads();   // protect LDS overwrite after gather

        // ---- phase A: evaluate each input value once ----
        #pragma unroll
        for (int v = tid; v < NV; v += 256) {
            const int r  = v / LW;
            const int cc = v - r * LW;
            const int iy = ty0 + r, ix = tx0 + cc;
            const float val = (iy < H && ix < W) ? xc[iy * W + ix] : 0.f;

            const float sil = silu(val);
            const float tf  = (val - g0) * invh;
            const float tfl = floorf(tf);
            const int   ti  = (int)tfl;
            const float u   = tf - tfl;
            const bool  valid = ((unsigned)ti < (unsigned)N_INT);
            const int   tc  = valid ? ti : 0;

            #pragma unroll
            for (int p = 0; p < IN_F; ++p) {
                const float4 cf = coef[tc][p];
                float sp = fmaf(u, cf.w, cf.z);
                sp = fmaf(u, sp, cf.y);
                sp = fmaf(u, sp, cf.x);
                sfeat[p][v] = fmaf(sil, bw[p], valid ? sp : 0.f);
            }
        }
        __syncthreads();

        // ---- phase B: gather 4 window neighbors ----
        const int i00 = ly * LW + lx;
        acc += sfeat[0][i00] + sfeat[1][i00 + 1]
             + sfeat[2][i00 + LW] + sfeat[3][i00 + LW + 1];
    }

    if (oy < Ho && ox < Wo)
        out[((size_t)b * Ho + oy) * Wo + ox] = acc;
}

extern "C" void kernel_launch(void* const* d_in, const int* in_sizes, int n_in,
                              void* d_out, int out_size, void* d_ws, size_t ws_size,
                              hipStream_t stream) {
    const float* x        = (const float*)d_in[0];
    const float* base_w   = (const float*)d_in[1];
    const float* spline_w = (const float*)d_in[2];
    const float* spline_s = (const float*)d_in[3];
    const float* grid     = (const float*)d_in[4];
    float* out = (float*)d_out;

    const int B = 8, C = 16, H = 128, W = 128;

    // 8 batches x 16 ytiles x 4 xtiles = 512 blocks
    kan_conv_kernel<<<512, 256, 0, stream>>>(
        x, base_w, spline_w, spline_s, grid, out, B, C, H, W);
}